// Round 1
// 532.596 us; speedup vs baseline: 1.0241x; 1.0241x over previous
//
#include <hip/hip_runtime.h>
#include <math.h>

#define TT 10
#define BB 32
#define CIN 3
#define COUT 64
#define HH 64
#define WW 64
#define HW (HH*WW)           // 4096
#define DECAY 0.2f
#define INH 1.625f

__device__ __forceinline__ unsigned int enc_f(float f) {
    unsigned int u = __float_as_uint(f);
    return (u & 0x80000000u) ? ~u : (u | 0x80000000u);
}
__device__ __forceinline__ float dec_f(unsigned int u) {
    u = (u & 0x80000000u) ? (u & 0x7FFFFFFFu) : ~u;
    return __uint_as_float(u);
}

// ---------------------------------------------------------------------------
// Pass 1: conv for the threshold max ONLY — no i stores (compute-bound).
// Same FMA ordering as pass 2 -> bitwise-identical i values.
// lane = channel (W[27] in VGPRs), wave = row within a 4-row group.
// Grid (16 rowgroups, B, T) x 256.
// ---------------------------------------------------------------------------
__global__ __launch_bounds__(256) void thr_kernel(
    const float* __restrict__ x,        // (T,B,3,64,64)
    const float* __restrict__ Wt,       // (64,3,3,3)
    unsigned int* __restrict__ thr_raw) // (T,64) pre-zeroed
{
    __shared__ float sx[CIN][6][68];    // row stride 68 -> 16B-aligned rows
    __shared__ float wmax[4][COUT];

    const int tid  = threadIdx.x;
    const int lane = tid & 63;          // channel
    const int wave = tid >> 6;          // row within 4-row group
    const int h0   = blockIdx.x * 4;
    const int b    = blockIdx.y;
    const int t    = blockIdx.z;

    float w[27];
    #pragma unroll
    for (int k = 0; k < 27; k++) w[k] = Wt[lane * 27 + k];

    // stage x tile (3 x 6 x 66 used cols), coalesced, zero-padded
    const float* xb = x + ((size_t)t * BB + b) * (CIN * HW);
    for (int l = tid; l < CIN * 6 * 66; l += 256) {
        int ci  = l / 396;
        int r   = (l % 396) / 66;
        int col = l % 66;
        int gh = h0 + r - 1;
        int gw = col - 1;
        float v = 0.f;
        if (gh >= 0 && gh < HH && gw >= 0 && gw < WW)
            v = xb[ci * HW + gh * WW + gw];
        sx[ci][r][col] = v;
    }
    __syncthreads();

    float mx = -INFINITY;

    for (int cc = 0; cc < 16; cc++) {          // 4-pixel chunks along the row
        float acc0 = 0.f, acc1 = 0.f, acc2 = 0.f, acc3 = 0.f;
        #pragma unroll
        for (int ci = 0; ci < CIN; ci++)
            #pragma unroll
            for (int kh = 0; kh < 3; kh++) {
                // wave-uniform LDS reads: broadcast, conflict-free
                const float* rp = &sx[ci][wave + kh][cc * 4];
                float4 q = *(const float4*)rp;
                float2 r2 = *(const float2*)(rp + 4);
                float x0 = q.x, x1 = q.y, x2 = q.z, x3 = q.w;
                float x4 = r2.x, x5 = r2.y;
                const float w0 = w[ci * 9 + kh * 3 + 0];
                const float w1 = w[ci * 9 + kh * 3 + 1];
                const float w2 = w[ci * 9 + kh * 3 + 2];
                acc0 = fmaf(w0, x0, acc0); acc0 = fmaf(w1, x1, acc0); acc0 = fmaf(w2, x2, acc0);
                acc1 = fmaf(w0, x1, acc1); acc1 = fmaf(w1, x2, acc1); acc1 = fmaf(w2, x3, acc1);
                acc2 = fmaf(w0, x2, acc2); acc2 = fmaf(w1, x3, acc2); acc2 = fmaf(w2, x4, acc2);
                acc3 = fmaf(w0, x3, acc3); acc3 = fmaf(w1, x4, acc3); acc3 = fmaf(w2, x5, acc3);
            }
        mx = fmaxf(mx, fmaxf(fmaxf(acc0, acc1), fmaxf(acc2, acc3)));
    }

    wmax[wave][lane] = mx;
    __syncthreads();
    if (wave == 0) {
        float m = fmaxf(fmaxf(wmax[0][lane], wmax[1][lane]),
                        fmaxf(wmax[2][lane], wmax[3][lane]));
        atomicMax(&thr_raw[t * COUT + lane], enc_f(m));
    }
}

// ---------------------------------------------------------------------------
// Pass 2: fused conv + LIF. No ibuf — conv recomputed into registers from a
// per-(b,h) LDS x-tile (3ch x 3rows x 66cols per t, ~2.4 KB). Same FMA order
// as pass 1 -> bitwise-identical i. lane = channel; wave owns 16 pixels;
// mem[16] in registers across all t. WTA = ballot-gated butterfly; output =
// coalesced zero-fill + sparse winner stores (r7-proven epilogue).
// Grid = B*H = 2048 blocks x 256.
// ---------------------------------------------------------------------------
__global__ __launch_bounds__(256) void fused_kernel(
    const float* __restrict__ x,              // (T,B,3,64,64)
    const float* __restrict__ Wt,             // (64,3,3,3)
    const unsigned int* __restrict__ thr_raw, // (T,64)
    float* __restrict__ out)                  // (T,B,64,64,64)
{
    __shared__ float sx[CIN][3][68];          // rows h-1..h+1, 16B-aligned rows

    const int tid  = threadIdx.x;
    const int lane = tid & 63;                            // channel
    const int wave = tid >> 6;
    const int p0   = __builtin_amdgcn_readfirstlane(wave * 16);
    const int b    = blockIdx.x >> 6;
    const int h    = blockIdx.x & 63;

    float w[27];
    #pragma unroll
    for (int k = 0; k < 27; k++) w[k] = Wt[lane * 27 + k];

    float mem[16];
    #pragma unroll
    for (int j = 0; j < 16; j++) mem[j] = 0.f;

    #pragma unroll 1
    for (int t = 0; t < TT; t++) {
        // stage x rows h-1..h+1 (3 ch x 3 rows x 66 cols), zero-padded
        const float* xb = x + ((size_t)t * BB + b) * (CIN * HW);
        for (int l = tid; l < CIN * 3 * 66; l += 256) {
            int ci  = l / 198;
            int r   = (l % 198) / 66;
            int col = l % 66;
            int gh = h + r - 1;
            int gw = col - 1;
            float v = 0.f;
            if (gh >= 0 && gh < HH && gw >= 0 && gw < WW)
                v = xb[ci * HW + gh * WW + gw];
            sx[ci][r][col] = v;
        }

        float* os = out + (((size_t)t * BB + b) * COUT) * HW + h * WW;

        // coalesced zero-fill of this block's (t,b,:,h,:) slab
        #pragma unroll
        for (int g = 0; g < 4; g++) {
            int c  = g * 16 + (tid >> 4);
            int w4 = (tid & 15) * 4;
            *(float4*)(os + (size_t)c * HW + w4) = make_float4(0.f, 0.f, 0.f, 0.f);
        }

        __syncthreads();   // sx visible; zero-fill drained (vmcnt0 at barrier)

        // per-lane (= per-channel) threshold constants
        float thr   = dec_f(thr_raw[t * COUT + lane]) + 1e-4f;
        float sinv  = 8.0f / thr;
        float s04   = 0.4f * thr;
        float sinh_ = INH * thr;

        int fmask = 0;     // bit j: this lane's channel fired at pixel p0+j

#define LIF_PX(J, ACC) {                                                    \
        float cur = fmaxf(ACC, 0.f);                                        \
        float z   = (cur - s04) * sinv;                                     \
        float sig = 1.0f / (1.0f + expf(-z));                               \
        float m   = mem[J] * DECAY + thr * sig;                             \
        int   sp  = m > thr;                                                \
        float score = sp ? m : 0.f;                                         \
        unsigned long long blt = __ballot(sp);                              \
        int fr = 0, sp_any = 0;                                             \
        if (blt) {   /* wave-uniform; rare */                               \
            float bs = score;                                               \
            int   bc = lane;                                                \
            _Pragma("unroll")                                               \
            for (int off = 32; off > 0; off >>= 1) {                        \
                float so = __shfl_xor(bs, off, 64);                         \
                int   co = __shfl_xor(bc, off, 64);                         \
                if (so > bs || (so == bs && co < bc)) { bs = so; bc = co; } \
            }                                                               \
            int spw = __shfl(sp, bc, 64);   /* winner's spike = any_sp */   \
            fr     = (lane == bc) && sp;                                    \
            sp_any = spw;                                                   \
        }                                                                   \
        mem[J] = fr ? 0.f : (m - (sp_any ? sinh_ : 0.f));                   \
        if (fr) fmask |= (1 << (J));                                        \
    }

        #pragma unroll
        for (int ch = 0; ch < 4; ch++) {       // 4-pixel chunks of this wave
            const int c0 = p0 + ch * 4;        // chunk start pixel
            float acc0 = 0.f, acc1 = 0.f, acc2 = 0.f, acc3 = 0.f;
            #pragma unroll
            for (int ci = 0; ci < CIN; ci++)
                #pragma unroll
                for (int kh = 0; kh < 3; kh++) {
                    // wave-uniform LDS reads: broadcast, conflict-free
                    const float* rp = &sx[ci][kh][c0];
                    float4 q = *(const float4*)rp;
                    float2 r2 = *(const float2*)(rp + 4);
                    float x0 = q.x, x1 = q.y, x2 = q.z, x3 = q.w;
                    float x4 = r2.x, x5 = r2.y;
                    const float w0 = w[ci * 9 + kh * 3 + 0];
                    const float w1 = w[ci * 9 + kh * 3 + 1];
                    const float w2 = w[ci * 9 + kh * 3 + 2];
                    acc0 = fmaf(w0, x0, acc0); acc0 = fmaf(w1, x1, acc0); acc0 = fmaf(w2, x2, acc0);
                    acc1 = fmaf(w0, x1, acc1); acc1 = fmaf(w1, x2, acc1); acc1 = fmaf(w2, x3, acc1);
                    acc2 = fmaf(w0, x2, acc2); acc2 = fmaf(w1, x3, acc2); acc2 = fmaf(w2, x4, acc2);
                    acc3 = fmaf(w0, x3, acc3); acc3 = fmaf(w1, x4, acc3); acc3 = fmaf(w2, x5, acc3);
                }
            LIF_PX(ch * 4 + 0, acc0);
            LIF_PX(ch * 4 + 1, acc1);
            LIF_PX(ch * 4 + 2, acc2);
            LIF_PX(ch * 4 + 3, acc3);
        }
#undef LIF_PX

        // sparse winner stores (rare) — zero-fill already drained at barrier
        if (fmask) {
            #pragma unroll
            for (int j = 0; j < 16; j++)
                if (fmask & (1 << j))
                    os[(size_t)lane * HW + p0 + j] = 1.0f;
        }
        __syncthreads();   // protect sx before next t's staging
    }
}

// ---------------------------------------------------------------------------
extern "C" void kernel_launch(void* const* d_in, const int* in_sizes, int n_in,
                              void* d_out, int out_size, void* d_ws, size_t ws_size,
                              hipStream_t stream) {
    const float* x = (const float*)d_in[0];   // (T,B,3,64,64)
    const float* W = (const float*)d_in[1];   // (64,3,3,3)
    float* out     = (float*)d_out;           // (T,B,64,64,64)

    unsigned int* thr = (unsigned int*)d_ws;  // (T,64) — only 2.5 KB of ws used
    hipMemsetAsync(thr, 0, TT * COUT * sizeof(unsigned int), stream);

    thr_kernel<<<dim3(HH / 4, BB, TT), 256, 0, stream>>>(x, W, thr);
    fused_kernel<<<dim3(BB * HH), 256, 0, stream>>>(x, W, thr, out);
}